// Round 3
// baseline (238.917 us; speedup 1.0000x reference)
//
#include <hip/hip_runtime.h>

// Hopf oscillator scan.
// X_r, X_i: [bs=8, T=64, d=32, d=32, nk=32] fp32; omegas: [32,32,32].
// Outputs: (r*cos(phi), r*sin(phi)) each [8,64,32,32,32], concatenated.
// 262,144 independent chains over (bs,d,d,nk); T sequential.
//
// R7: drop nontemporal hints (A/B vs R6, single variable). R4-R6 all carried
// NT loads+stores and all plateaued at 3.2-3.7 TB/s despite width (dword ->
// dwordx2 -> dwordx4) and occupancy (1-4 waves/SIMD) changes, with in-flight
// bytes far above the Little's-law requirement. The 6.29 TB/s copy ceiling
// (m13) and the 6.6 TB/s harness fills both use CACHED accesses: L2
// aggregates wave requests into full-rate HBM bursts and acks stores at
// write-back speed. NT bypasses that path. Streamed-once data loses nothing
// by going through L2. Structure otherwise identical to R6: 2 chains/thread,
// dwordx2 (512 B/wave-inst), 131072 threads = 2 waves/SIMD, DEPTH=16.
// Trig via small-angle rotation (R3). Full unroll of T=64.

#define T_STEPS 64
#define CHV2    16384         // float2-chains per batch image (32768 / 2)
#define BS      8
#define DEPTH   16            // pipeline depth in t-steps (2 x dwordx2 per step)

typedef float v2f __attribute__((ext_vector_type(2)));

__global__ __launch_bounds__(256)
void hopf_scan_kernel(const float* __restrict__ Xr,
                      const float* __restrict__ Xi,
                      const float* __restrict__ Om,
                      float* __restrict__ out)
{
    const float DT = 0.01f;
    const float SC = 20.0f;
    // sin(x) = x*(1 + u*(S1 + u*(S2 + u*(S3 + u*S4)))), u = x^2
    const float S1 = -1.6666667e-1f, S2 = 8.3333333e-3f,
                S3 = -1.9841270e-4f, S4 = 2.7557319e-6f;
    // cos(x) = 1 + u*(C1 + u*(C2 + u*(C3 + u*C4)))
    const float C1 = -0.5f, C2 = 4.1666667e-2f,
                C3 = -1.3888889e-3f, C4 = 2.4801587e-5f;

    const v2f* __restrict__ vXr = (const v2f*)Xr;
    const v2f* __restrict__ vXi = (const v2f*)Xi;
    const v2f* __restrict__ vOm = (const v2f*)Om;
    v2f* __restrict__ vout      = (v2f*)out;

    int tid = blockIdx.x * blockDim.x + threadIdx.x;   // 0 .. 131071
    int b   = tid >> 14;                               // CHV2 = 16384 vec-chains
    int cv  = tid & (CHV2 - 1);

    v2f om = vOm[cv];

    const size_t stride = CHV2;                        // v2f elements per t
    size_t base = (size_t)(b * T_STEPS) * stride + cv;
    const v2f* pxr = vXr + base;
    const v2f* pxi = vXi + base;
    v2f* po0 = vout + base;
    v2f* po1 = po0 + (size_t)BS * T_STEPS * stride;

    float r[2]  = {1.f, 1.f};
    float co[2] = {1.f, 1.f};
    float si[2] = {0.f, 0.f};                          // phi0 = 0

    // prime: loads for t = 0..DEPTH-1 (32 dwordx2 loads in flight)
    v2f xr[DEPTH], xi[DEPTH];
    #pragma unroll
    for (int i = 0; i < DEPTH; ++i) {
        xr[i] = pxr[(size_t)i * stride];
        xi[i] = pxi[(size_t)i * stride];
    }

    #pragma unroll
    for (int t = 0; t < T_STEPS; ++t) {
        const int s = t & (DEPTH - 1);                 // static after unroll
        v2f axr = xr[s];
        v2f axi = xi[s];
        // refill the slot immediately: load for t+DEPTH goes in flight now,
        // consumed DEPTH steps later.
        if (t + DEPTH < T_STEPS) {
            xr[s] = pxr[(size_t)(t + DEPTH) * stride];
            xi[s] = pxi[(size_t)(t + DEPTH) * stride];
        }

        v2f o0, o1;
        #pragma unroll
        for (int j = 0; j < 2; ++j) {
            float ir   = SC * axr[j] * co[j];                // old cos
            float dphi = (om[j] - SC * axi[j] * si[j]) * DT; // old sin
            r[j] = r[j] + ((1.f - r[j] * r[j]) * r[j] + ir) * DT;

            float u  = dphi * dphi;
            float sp = fmaf(u, S4, S3);
            sp = fmaf(u, sp, S2);
            sp = fmaf(u, sp, S1);
            sp = fmaf(u, sp, 1.f);
            sp *= dphi;                                      // sin(dphi)
            float cp = fmaf(u, C4, C3);
            cp = fmaf(u, cp, C2);
            cp = fmaf(u, cp, C1);
            cp = fmaf(u, cp, 1.f);                           // cos(dphi)

            float nco = fmaf(co[j], cp, -si[j] * sp);
            float nsi = fmaf(si[j], cp,  co[j] * sp);
            co[j] = nco; si[j] = nsi;

            o0[j] = r[j] * co[j];
            o1[j] = r[j] * si[j];
        }

        size_t off = (size_t)t * stride;
        po0[off] = o0;
        po1[off] = o1;
    }
}

extern "C" void kernel_launch(void* const* d_in, const int* in_sizes, int n_in,
                              void* d_out, int out_size, void* d_ws, size_t ws_size,
                              hipStream_t stream) {
    const float* Xr = (const float*)d_in[0];
    const float* Xi = (const float*)d_in[1];
    const float* Om = (const float*)d_in[2];
    float* out = (float*)d_out;

    dim3 block(256);
    dim3 grid(BS * CHV2 / 256);   // 512 blocks = 131072 threads, 2 chains each
    hopf_scan_kernel<<<grid, block, 0, stream>>>(Xr, Xi, Om, out);
}

// Round 5
// 238.294 us; speedup vs baseline: 1.0026x; 1.0026x over previous
//
#include <hip/hip_runtime.h>

// Hopf oscillator scan.
// X_r, X_i: [bs=8, T=64, d=32, d=32, nk=32] fp32; omegas: [32,32,32].
// Outputs: (r*cos(phi), r*sin(phi)) each [8,64,32,32,32], concatenated.
// 262,144 independent chains over (bs,d,d,nk); T sequential.
//
// R8b: hand-owned VMEM schedule (R8 resubmit, hardened after infra failure).
// R4-R7 plateaued at ~3.2-3.7 TB/s; R7's VGPR_Count=48 proved the compiler
// collapsed the software pipeline (DEPTH=16 x v2f needs 64 VGPRs of buffers
// alone), keeping only ~2-4 loads in flight per wave -> Little's-law-pinned.
// Fix: all loads/stores via asm volatile (issue order = program order,
// un-sinkable, buffers forced live) with exact counted s_waitcnt vmcnt(N)
// per step + sched_barrier(0) fence (guide rule #18).
// Hardened vs R8: DEPTH=12 keeps max outstanding VMEM ops at 50 <= 63
// (vmcnt cap; D=16 hit 64-66 and stalled at the counter cap each step),
// and __launch_bounds__(256,2) pins regalloc to 2 blocks/CU (grid = 512
// blocks on 256 CUs). Loads cached (L3 serves re-read inputs: R7 FETCH
// showed 50% residency), stores nt (don't evict resident inputs).
// Wait counts (D=12): fill t<12: N=22+2t; steady 12<=t<=52: N=46 (retires
// exactly the two loads for step t); drain t>52: N=46-2*(t-52).

#define T_STEPS 64
#define CHV2    16384         // float2-chains per batch image (32768 / 2)
#define BS      8
#define DEPTH   12            // pipeline depth in t-steps

typedef float v2f __attribute__((ext_vector_type(2)));

template<int i>
__device__ __forceinline__ void prime_loads(const v2f* pxr, const v2f* pxi,
                                            v2f (&xr)[DEPTH], v2f (&xi)[DEPTH])
{
    if constexpr (i < DEPTH) {
        asm volatile("global_load_dwordx2 %0, %1, off"
                     : "=v"(xr[i]) : "v"(pxr + (size_t)i * CHV2));
        asm volatile("global_load_dwordx2 %0, %1, off"
                     : "=v"(xi[i]) : "v"(pxi + (size_t)i * CHV2));
        prime_loads<i + 1>(pxr, pxi, xr, xi);
    }
}

template<int t>
__device__ __forceinline__ void steps(const v2f* pxr, const v2f* pxi,
                                      v2f* po0, v2f* po1,
                                      const float (&om)[2],
                                      float (&r)[2], float (&co)[2], float (&si)[2],
                                      v2f (&xr)[DEPTH], v2f (&xi)[DEPTH])
{
    if constexpr (t < T_STEPS) {
        const float DTS = 0.01f;
        const float SC  = 20.0f;
        // sin(x) = x*(1 + u*(S1 + u*(S2 + u*(S3 + u*S4)))), u = x^2
        const float S1 = -1.6666667e-1f, S2 = 8.3333333e-3f,
                    S3 = -1.9841270e-4f, S4 = 2.7557319e-6f;
        // cos(x) = 1 + u*(C1 + u*(C2 + u*(C3 + u*C4)))
        const float C1 = -0.5f, C2 = 4.1666667e-2f,
                    C3 = -1.3888889e-3f, C4 = 2.4801587e-5f;

        constexpr int s = t % DEPTH;
        // Exact outstanding-op count such that waiting to N retires exactly
        // the two loads belonging to step t. Max 50 outstanding before the
        // wait (24 ld + 24 st + 2 ld + ... ), comfortably under vmcnt cap 63.
        constexpr int N = (t < DEPTH) ? (2 * DEPTH - 2 + 2 * t)
                        : (t <= T_STEPS - DEPTH) ? (4 * DEPTH - 2)
                        : (4 * DEPTH - 2 - 2 * (t - (T_STEPS - DEPTH)));
        asm volatile("s_waitcnt vmcnt(%0)" :: "i"(N));
        __builtin_amdgcn_sched_barrier(0);

        v2f axr = xr[s];
        v2f axi = xi[s];
        // refill the slot: load for t+DEPTH goes in flight now, consumed
        // DEPTH steps later -> 24 loads (12 KiB) in flight per wave.
        if constexpr (t + DEPTH < T_STEPS) {
            asm volatile("global_load_dwordx2 %0, %1, off"
                         : "=v"(xr[s]) : "v"(pxr + (size_t)(t + DEPTH) * CHV2));
            asm volatile("global_load_dwordx2 %0, %1, off"
                         : "=v"(xi[s]) : "v"(pxi + (size_t)(t + DEPTH) * CHV2));
        }

        v2f o0, o1;
        #pragma unroll
        for (int j = 0; j < 2; ++j) {
            float ir   = SC * axr[j] * co[j];                 // old cos
            float dphi = (om[j] - SC * axi[j] * si[j]) * DTS; // old sin
            r[j] = r[j] + ((1.f - r[j] * r[j]) * r[j] + ir) * DTS;

            float u  = dphi * dphi;
            float sp = fmaf(u, S4, S3);
            sp = fmaf(u, sp, S2);
            sp = fmaf(u, sp, S1);
            sp = fmaf(u, sp, 1.f);
            sp *= dphi;                                       // sin(dphi)
            float cp = fmaf(u, C4, C3);
            cp = fmaf(u, cp, C2);
            cp = fmaf(u, cp, C1);
            cp = fmaf(u, cp, 1.f);                            // cos(dphi)

            float nco = fmaf(co[j], cp, -si[j] * sp);
            float nsi = fmaf(si[j], cp,  co[j] * sp);
            co[j] = nco; si[j] = nsi;

            o0[j] = r[j] * co[j];
            o1[j] = r[j] * si[j];
        }

        asm volatile("global_store_dwordx2 %0, %1, off nt"
                     :: "v"(po0 + (size_t)t * CHV2), "v"(o0));
        asm volatile("global_store_dwordx2 %0, %1, off nt"
                     :: "v"(po1 + (size_t)t * CHV2), "v"(o1));

        steps<t + 1>(pxr, pxi, po0, po1, om, r, co, si, xr, xi);
    }
}

__global__ __launch_bounds__(256, 2)
void hopf_scan_kernel(const float* __restrict__ Xr,
                      const float* __restrict__ Xi,
                      const float* __restrict__ Om,
                      float* __restrict__ out)
{
    const v2f* __restrict__ vXr = (const v2f*)Xr;
    const v2f* __restrict__ vXi = (const v2f*)Xi;
    const v2f* __restrict__ vOm = (const v2f*)Om;
    v2f* __restrict__ vout      = (v2f*)out;

    int tid = blockIdx.x * blockDim.x + threadIdx.x;   // 0 .. 131071
    int b   = tid >> 14;                               // CHV2 = 16384 vec-chains
    int cv  = tid & (CHV2 - 1);

    // Load omegas; the dummy asm forces materialization (and the compiler's
    // own vmcnt wait) BEFORE our hand-counted asm ops, keeping counts exact.
    v2f omv = vOm[cv];
    float om[2] = {omv[0], omv[1]};
    asm volatile("" :: "v"(om[0]), "v"(om[1]));

    const size_t stride = CHV2;                        // v2f elements per t
    size_t base = (size_t)(b * T_STEPS) * stride + cv;
    const v2f* pxr = vXr + base;
    const v2f* pxi = vXi + base;
    v2f* po0 = vout + base;
    v2f* po1 = po0 + (size_t)BS * T_STEPS * stride;

    float r[2]  = {1.f, 1.f};
    float co[2] = {1.f, 1.f};
    float si[2] = {0.f, 0.f};                          // phi0 = 0

    v2f xr[DEPTH], xi[DEPTH];
    prime_loads<0>(pxr, pxi, xr, xi);                  // 24 loads in flight

    steps<0>(pxr, pxi, po0, po1, om, r, co, si, xr, xi);
}

extern "C" void kernel_launch(void* const* d_in, const int* in_sizes, int n_in,
                              void* d_out, int out_size, void* d_ws, size_t ws_size,
                              hipStream_t stream) {
    const float* Xr = (const float*)d_in[0];
    const float* Xi = (const float*)d_in[1];
    const float* Om = (const float*)d_in[2];
    float* out = (float*)d_out;

    dim3 block(256);
    dim3 grid(BS * CHV2 / 256);   // 512 blocks = 131072 threads, 2 chains each
    hopf_scan_kernel<<<grid, block, 0, stream>>>(Xr, Xi, Om, out);
}

// Round 6
// 229.950 us; speedup vs baseline: 1.0390x; 1.0363x over previous
//
#include <hip/hip_runtime.h>

// Hopf oscillator scan.
// X_r, X_i: [bs=8, T=64, d=32, d=32, nk=32] fp32; omegas: [32,32,32].
// Outputs: (r*cos(phi), r*sin(phi)) each [8,64,32,32,32], concatenated.
// 262,144 independent chains over (bs,d,d,nk); T sequential.
//
// R9: NT loads (single-variable A/B vs R8b). Cross-round matrix:
//   NT loads   (R5/R6, compiler pipeline): 66-72 us kernel
//   cached lds (R7 compiler, R8b hand)   : 83-85 us kernel
// -> load cache policy is the lever, not pipeline depth/width. Cached loads
// serve ~half the input from L3 (R7/R8b FETCH=65.7MB) but the L2/L3-allocate
// read path contends with the 128MB store stream through 4MiB/XCD L2 and
// runs SLOWER than streaming from HBM. NT bypasses the caches on both sides.
// Keep the hand-owned VMEM schedule from R8b (asm volatile, counted
// s_waitcnt vmcnt(N) + sched_barrier(0), rule #18): if its 24-deep MLP
// multiplies with the NT path we go <60us; if we land at R6's ~66-72 the
// pipeline is formally exonerated and the remaining gap vs the 42.6us copy
// roofline is mixed-R/W structural cost.
// Wait counts (D=12): fill t<12: N=22+2t; steady: N=46 (retires exactly the
// 2 loads + 2 stores due); drain t>52: N=46-2*(t-52). Max outstanding 50<=63.

#define T_STEPS 64
#define CHV2    16384         // float2-chains per batch image (32768 / 2)
#define BS      8
#define DEPTH   12            // pipeline depth in t-steps

typedef float v2f __attribute__((ext_vector_type(2)));

template<int i>
__device__ __forceinline__ void prime_loads(const v2f* pxr, const v2f* pxi,
                                            v2f (&xr)[DEPTH], v2f (&xi)[DEPTH])
{
    if constexpr (i < DEPTH) {
        asm volatile("global_load_dwordx2 %0, %1, off nt"
                     : "=v"(xr[i]) : "v"(pxr + (size_t)i * CHV2));
        asm volatile("global_load_dwordx2 %0, %1, off nt"
                     : "=v"(xi[i]) : "v"(pxi + (size_t)i * CHV2));
        prime_loads<i + 1>(pxr, pxi, xr, xi);
    }
}

template<int t>
__device__ __forceinline__ void steps(const v2f* pxr, const v2f* pxi,
                                      v2f* po0, v2f* po1,
                                      const float (&om)[2],
                                      float (&r)[2], float (&co)[2], float (&si)[2],
                                      v2f (&xr)[DEPTH], v2f (&xi)[DEPTH])
{
    if constexpr (t < T_STEPS) {
        const float DTS = 0.01f;
        const float SC  = 20.0f;
        // sin(x) = x*(1 + u*(S1 + u*(S2 + u*(S3 + u*S4)))), u = x^2
        const float S1 = -1.6666667e-1f, S2 = 8.3333333e-3f,
                    S3 = -1.9841270e-4f, S4 = 2.7557319e-6f;
        // cos(x) = 1 + u*(C1 + u*(C2 + u*(C3 + u*C4)))
        const float C1 = -0.5f, C2 = 4.1666667e-2f,
                    C3 = -1.3888889e-3f, C4 = 2.4801587e-5f;

        constexpr int s = t % DEPTH;
        // Wait so that exactly the ops belonging to step t have retired.
        constexpr int N = (t < DEPTH) ? (2 * DEPTH - 2 + 2 * t)
                        : (t <= T_STEPS - DEPTH) ? (4 * DEPTH - 2)
                        : (4 * DEPTH - 2 - 2 * (t - (T_STEPS - DEPTH)));
        asm volatile("s_waitcnt vmcnt(%0)" :: "i"(N));
        __builtin_amdgcn_sched_barrier(0);

        v2f axr = xr[s];
        v2f axi = xi[s];
        // refill the slot: load for t+DEPTH goes in flight now, consumed
        // DEPTH steps later -> 24 loads (12 KiB) in flight per wave.
        if constexpr (t + DEPTH < T_STEPS) {
            asm volatile("global_load_dwordx2 %0, %1, off nt"
                         : "=v"(xr[s]) : "v"(pxr + (size_t)(t + DEPTH) * CHV2));
            asm volatile("global_load_dwordx2 %0, %1, off nt"
                         : "=v"(xi[s]) : "v"(pxi + (size_t)(t + DEPTH) * CHV2));
        }

        v2f o0, o1;
        #pragma unroll
        for (int j = 0; j < 2; ++j) {
            float ir   = SC * axr[j] * co[j];                 // old cos
            float dphi = (om[j] - SC * axi[j] * si[j]) * DTS; // old sin
            r[j] = r[j] + ((1.f - r[j] * r[j]) * r[j] + ir) * DTS;

            float u  = dphi * dphi;
            float sp = fmaf(u, S4, S3);
            sp = fmaf(u, sp, S2);
            sp = fmaf(u, sp, S1);
            sp = fmaf(u, sp, 1.f);
            sp *= dphi;                                       // sin(dphi)
            float cp = fmaf(u, C4, C3);
            cp = fmaf(u, cp, C2);
            cp = fmaf(u, cp, C1);
            cp = fmaf(u, cp, 1.f);                            // cos(dphi)

            float nco = fmaf(co[j], cp, -si[j] * sp);
            float nsi = fmaf(si[j], cp,  co[j] * sp);
            co[j] = nco; si[j] = nsi;

            o0[j] = r[j] * co[j];
            o1[j] = r[j] * si[j];
        }

        asm volatile("global_store_dwordx2 %0, %1, off nt"
                     :: "v"(po0 + (size_t)t * CHV2), "v"(o0));
        asm volatile("global_store_dwordx2 %0, %1, off nt"
                     :: "v"(po1 + (size_t)t * CHV2), "v"(o1));

        steps<t + 1>(pxr, pxi, po0, po1, om, r, co, si, xr, xi);
    }
}

__global__ __launch_bounds__(256, 2)
void hopf_scan_kernel(const float* __restrict__ Xr,
                      const float* __restrict__ Xi,
                      const float* __restrict__ Om,
                      float* __restrict__ out)
{
    const v2f* __restrict__ vXr = (const v2f*)Xr;
    const v2f* __restrict__ vXi = (const v2f*)Xi;
    const v2f* __restrict__ vOm = (const v2f*)Om;
    v2f* __restrict__ vout      = (v2f*)out;

    int tid = blockIdx.x * blockDim.x + threadIdx.x;   // 0 .. 131071
    int b   = tid >> 14;                               // CHV2 = 16384 vec-chains
    int cv  = tid & (CHV2 - 1);

    // Load omegas (cached -- tiny and reused across blocks); the dummy asm
    // forces its materialization (and the compiler's vmcnt wait) BEFORE our
    // hand-counted asm ops, keeping counts exact.
    v2f omv = vOm[cv];
    float om[2] = {omv[0], omv[1]};
    asm volatile("" :: "v"(om[0]), "v"(om[1]));

    const size_t stride = CHV2;                        // v2f elements per t
    size_t base = (size_t)(b * T_STEPS) * stride + cv;
    const v2f* pxr = vXr + base;
    const v2f* pxi = vXi + base;
    v2f* po0 = vout + base;
    v2f* po1 = po0 + (size_t)BS * T_STEPS * stride;

    float r[2]  = {1.f, 1.f};
    float co[2] = {1.f, 1.f};
    float si[2] = {0.f, 0.f};                          // phi0 = 0

    v2f xr[DEPTH], xi[DEPTH];
    prime_loads<0>(pxr, pxi, xr, xi);                  // 24 NT loads in flight

    steps<0>(pxr, pxi, po0, po1, om, r, co, si, xr, xi);
}

extern "C" void kernel_launch(void* const* d_in, const int* in_sizes, int n_in,
                              void* d_out, int out_size, void* d_ws, size_t ws_size,
                              hipStream_t stream) {
    const float* Xr = (const float*)d_in[0];
    const float* Xi = (const float*)d_in[1];
    const float* Om = (const float*)d_in[2];
    float* out = (float*)d_out;

    dim3 block(256);
    dim3 grid(BS * CHV2 / 256);   // 512 blocks = 131072 threads, 2 chains each
    hopf_scan_kernel<<<grid, block, 0, stream>>>(Xr, Xi, Om, out);
}

// Round 7
// 225.713 us; speedup vs baseline: 1.0585x; 1.0188x over previous
//
#include <hip/hip_runtime.h>

// Hopf oscillator scan.
// X_r, X_i: [bs=8, T=64, d=32, d=32, nk=32] fp32; omegas: [32,32,32].
// Outputs: (r*cos(phi), r*sin(phi)) each [8,64,32,32,32], concatenated.
// 262,144 independent chains over (bs,d,d,nk); T sequential.
//
// R10: NT loads + CACHED stores (the untested cell of the cache matrix).
//   NT ld + NT st      (R5/R6/R9): 71-75 us   <- NT-store path caps ~3.8 TB/s
//   cached ld + any st (R7/R8b)  : 83-85 us   <- load allocs thrash L2 vs stores
//   store-only cached (harness fill): 6.6 TB/s at 3 waves/CU
// Theory: NT stores retire at HBM speed and vmcnt retires in-order behind
// them; cached stores ack at L2 (the fill path) and write back async. NT
// loads keep L2 entirely free for the store stream. Hand vmcnt pipeline
// exonerated (R9 == R6 within noise): compiler scheduling retained.
// Structure = R6 verbatim: 2 chains/thread, dwordx2, 131072 threads
// (2 waves/SIMD), DEPTH=16 buffers, full unroll of T=64, small-angle trig.

#define T_STEPS 64
#define CHV2    16384         // float2-chains per batch image (32768 / 2)
#define BS      8
#define DEPTH   16            // pipeline depth in t-steps (2 x dwordx2 per step)

typedef float v2f __attribute__((ext_vector_type(2)));

__global__ __launch_bounds__(256)
void hopf_scan_kernel(const float* __restrict__ Xr,
                      const float* __restrict__ Xi,
                      const float* __restrict__ Om,
                      float* __restrict__ out)
{
    const float DT = 0.01f;
    const float SC = 20.0f;
    // sin(x) = x*(1 + u*(S1 + u*(S2 + u*(S3 + u*S4)))), u = x^2
    const float S1 = -1.6666667e-1f, S2 = 8.3333333e-3f,
                S3 = -1.9841270e-4f, S4 = 2.7557319e-6f;
    // cos(x) = 1 + u*(C1 + u*(C2 + u*(C3 + u*C4)))
    const float C1 = -0.5f, C2 = 4.1666667e-2f,
                C3 = -1.3888889e-3f, C4 = 2.4801587e-5f;

    const v2f* __restrict__ vXr = (const v2f*)Xr;
    const v2f* __restrict__ vXi = (const v2f*)Xi;
    const v2f* __restrict__ vOm = (const v2f*)Om;
    v2f* __restrict__ vout      = (v2f*)out;

    int tid = blockIdx.x * blockDim.x + threadIdx.x;   // 0 .. 131071
    int b   = tid >> 14;                               // CHV2 = 16384 vec-chains
    int cv  = tid & (CHV2 - 1);

    v2f om = vOm[cv];

    const size_t stride = CHV2;                        // v2f elements per t
    size_t base = (size_t)(b * T_STEPS) * stride + cv;
    const v2f* pxr = vXr + base;
    const v2f* pxi = vXi + base;
    v2f* po0 = vout + base;
    v2f* po1 = po0 + (size_t)BS * T_STEPS * stride;

    float r[2]  = {1.f, 1.f};
    float co[2] = {1.f, 1.f};
    float si[2] = {0.f, 0.f};                          // phi0 = 0

    // prime: loads for t = 0..DEPTH-1
    v2f xr[DEPTH], xi[DEPTH];
    #pragma unroll
    for (int i = 0; i < DEPTH; ++i) {
        xr[i] = __builtin_nontemporal_load(pxr + (size_t)i * stride);
        xi[i] = __builtin_nontemporal_load(pxi + (size_t)i * stride);
    }

    #pragma unroll
    for (int t = 0; t < T_STEPS; ++t) {
        const int s = t & (DEPTH - 1);                 // static after unroll
        v2f axr = xr[s];
        v2f axi = xi[s];
        // refill the slot: load for t+DEPTH goes in flight now, consumed
        // DEPTH steps later.
        if (t + DEPTH < T_STEPS) {
            xr[s] = __builtin_nontemporal_load(pxr + (size_t)(t + DEPTH) * stride);
            xi[s] = __builtin_nontemporal_load(pxi + (size_t)(t + DEPTH) * stride);
        }

        v2f o0, o1;
        #pragma unroll
        for (int j = 0; j < 2; ++j) {
            float ir   = SC * axr[j] * co[j];                // old cos
            float dphi = (om[j] - SC * axi[j] * si[j]) * DT; // old sin
            r[j] = r[j] + ((1.f - r[j] * r[j]) * r[j] + ir) * DT;

            float u  = dphi * dphi;
            float sp = fmaf(u, S4, S3);
            sp = fmaf(u, sp, S2);
            sp = fmaf(u, sp, S1);
            sp = fmaf(u, sp, 1.f);
            sp *= dphi;                                      // sin(dphi)
            float cp = fmaf(u, C4, C3);
            cp = fmaf(u, cp, C2);
            cp = fmaf(u, cp, C1);
            cp = fmaf(u, cp, 1.f);                           // cos(dphi)

            float nco = fmaf(co[j], cp, -si[j] * sp);
            float nsi = fmaf(si[j], cp,  co[j] * sp);
            co[j] = nco; si[j] = nsi;

            o0[j] = r[j] * co[j];
            o1[j] = r[j] * si[j];
        }

        size_t off = (size_t)t * stride;
        po0[off] = o0;                                 // cached store (fill path)
        po1[off] = o1;
    }
}

extern "C" void kernel_launch(void* const* d_in, const int* in_sizes, int n_in,
                              void* d_out, int out_size, void* d_ws, size_t ws_size,
                              hipStream_t stream) {
    const float* Xr = (const float*)d_in[0];
    const float* Xi = (const float*)d_in[1];
    const float* Om = (const float*)d_in[2];
    float* out = (float*)d_out;

    dim3 block(256);
    dim3 grid(BS * CHV2 / 256);   // 512 blocks = 131072 threads, 2 chains each
    hopf_scan_kernel<<<grid, block, 0, stream>>>(Xr, Xi, Om, out);
}